// Round 20
// baseline (177.065 us; speedup 1.0000x reference)
//
#include <hip/hip_runtime.h>
#include <hip/hip_bf16.h>

#define B_ 128
#define S_ 196
#define E_ 768
#define M_ 768
#define KTOT (S_*E_)            // 150528
#define BK 128                  // k per superstep
#define SS_TOTAL (KTOT/BK)      // 1176
#define KSPLIT 32
#define BN 48                   // m-rows per workgroup
#define MTN (M_/BN)             // 16
#define ZC 4                    // z-chunks in reduce

typedef __bf16 bf16x8 __attribute__((ext_vector_type(8)));
typedef float  f32x4  __attribute__((ext_vector_type(4)));

__device__ inline bf16x8 cvt8(const float* __restrict__ p) {
    float4 a = *(const float4*)p;
    float4 b = *(const float4*)(p + 4);
    bf16x8 r;
    r[0] = (__bf16)a.x; r[1] = (__bf16)a.y; r[2] = (__bf16)a.z; r[3] = (__bf16)a.w;
    r[4] = (__bf16)b.x; r[5] = (__bf16)b.y; r[6] = (__bf16)b.z; r[7] = (__bf16)b.w;
    return r;
}

__device__ inline bf16x8 cvt8v(float4 a, float4 b) {
    bf16x8 r;
    r[0] = (__bf16)a.x; r[1] = (__bf16)a.y; r[2] = (__bf16)a.z; r[3] = (__bf16)a.w;
    r[4] = (__bf16)b.x; r[5] = (__bf16)b.y; r[6] = (__bf16)b.z; r[7] = (__bf16)b.w;
    return r;
}

// HBM -> LDS direct, 16B per lane. Outstanding state lives in vmcnt + LDS,
// not VGPRs -- immune to register-pressure collapse (R18 failure mode).
__device__ inline void gload16(const float* g, void* l) {
    __builtin_amdgcn_global_load_lds(
        (const __attribute__((address_space(1))) void*)g,
        (__attribute__((address_space(3))) void*)l, 16, 0, 0);
}

__device__ inline void wait_and_barrier() {
    asm volatile("s_waitcnt vmcnt(0)" ::: "memory");
    asm volatile("s_waitcnt lgkmcnt(0)" ::: "memory");
    __builtin_amdgcn_s_barrier();
}

// ---------------- prep: init_out | event_pool | pack_a (block-partitioned) ----
// pack_a (BK=128 fragment order): chunk c = ((ss*8 + bt)*4 + kf)*64 + lane
// holds A[bt*16 + (lane&15)][ss*128 + kf*32 + (lane>>4)*8 .. +8)
__global__ void prep(const float* __restrict__ mlp_b,
                     const float* __restrict__ fk_b,
                     const float* __restrict__ A,
                     const int* __restrict__ BE, int be_stride,
                     float* __restrict__ out,
                     float* __restrict__ EP,
                     __bf16* __restrict__ Apk) {
    const int bid = blockIdx.x;
    if (bid < 384) {
        int i = bid * 256 + threadIdx.x;
        int m = i % M_;
        out[i] = 0.9f * mlp_b[m] + 0.1f * fk_b[m];
    } else if (bid < 512) {
        int b = bid - 384;
        int s1 = BE[(b*4 + 0) * be_stride];
        int e1 = BE[(b*4 + 1) * be_stride];
        int s2 = BE[(b*4 + 2) * be_stride];
        int e2 = BE[(b*4 + 3) * be_stride];
        float inv1 = 1.0f / (float)(e1 - s1);
        float inv2 = 1.0f / (float)(e2 - s2);
        for (int c = threadIdx.x; c < E_; c += 256) {
            float sum1 = 0.f, sum2 = 0.f;
            for (int s = s1; s < e1; ++s) sum1 += A[((size_t)b * S_ + s) * E_ + c];
            for (int s = s2; s < e2; ++s) sum2 += A[((size_t)b * S_ + s) * E_ + c];
            EP[b * (2*E_) + c]       = sum1 * inv1;
            EP[b * (2*E_) + E_ + c]  = sum2 * inv2;
        }
    } else {
        const int nchunk = SS_TOTAL * 8 * 4 * 64;   // 2,408,448
        for (int c = (bid - 512) * 256 + threadIdx.x; c < nchunk; c += 3072 * 256) {
            int lane = c & 63;
            int kf   = (c >> 6) & 3;
            int bt   = (c >> 8) & 7;
            int ss   = c >> 11;
            int b = bt * 16 + (lane & 15);
            int k = ss * BK + kf * 32 + (lane >> 4) * 8;
            *(bf16x8*)(Apk + (size_t)c * 8) = cvt8(A + (size_t)b * KTOT + k);
        }
    }
}

// ---------------- fk_gemm: partial[kz][b][m] ------------------------------
// 8 waves, tile 128b x 48m x 128k/ss. W staged HBM->LDS via global_load_lds
// (f32, 2 rows per instruction, 3 instr/wave/ss): 24 KB tile, dbuf 48 KB/wg,
// 2 wgs/CU => 48 KB/CU outstanding through every compute phase (vs ~9.2 KB
// needed for 6.3 TB/s at 900cy). One barrier/ss: vmcnt(0) -> s_barrier ->
// issue next tile -> compute. Source pre-swizzled by (row&7)<<4 so the linear
// LDS dest reads back bank-balanced with the same XOR (m173 pattern).
// A register-direct from packed frags; cvt f32->bf16 at the consumer.

#define ISSUE_W(sl, bb)                                                       \
    _Pragma("unroll")                                                         \
    for (int j = 0; j < 3; ++j) {                                             \
        const int row = wv * 6 + 2 * j + (lane >> 5);                         \
        const float* g = W + (size_t)(mt * BN + row) * KTOT                   \
                         + (size_t)(ss0 + (sl)) * BK                          \
                         + (((((lane & 31) * 16) ^ ((row & 7) << 4))) >> 2);  \
        gload16(g, &Wlds[bb][(wv * 6 + 2 * j) * 512]);                        \
    }

#define LOAD_A(sl)                                                            \
    _Pragma("unroll")                                                         \
    for (int kf = 0; kf < 4; ++kf)                                            \
        aA[kf] = *(const bf16x8*)(abase + (size_t)(sl) * 16384 + kf * 512);

#define COMPUTE(bb)                                                           \
    _Pragma("unroll")                                                         \
    for (int kf = 0; kf < 4; ++kf) {                                          \
        _Pragma("unroll")                                                     \
        for (int n = 0; n < 3; ++n) {                                         \
            const char* p = &Wlds[bb][(n * 16 + r16) * 512];                  \
            const int cb = kf * 128 + kg * 32;                                \
            float4 f0 = *(const float4*)(p + ((cb) ^ sw));                    \
            float4 f1 = *(const float4*)(p + ((cb + 16) ^ sw));               \
            bf16x8 wf = cvt8v(f0, f1);                                        \
            acc[n] = __builtin_amdgcn_mfma_f32_16x16x32_bf16(aA[kf], wf,      \
                                                             acc[n], 0, 0, 0);\
        }                                                                     \
    }

__global__ __launch_bounds__(512, 4) void fk_gemm(const __bf16* __restrict__ Apk,
                                                  const float* __restrict__ W,
                                                  float* __restrict__ partial) {
    __shared__ __align__(16) char Wlds[2][BN * 512];    // 2 x 24 KB, f32 rows

    const int wg   = blockIdx.x;        // 0..511
    const int xcd  = wg & 7;            // wg -> XCD round-robin (m09)
    const int slot = wg >> 3;           // 0..63 per-XCD sequence
    const int kz   = (slot >> 4) * 8 + xcd;  // 4 kz groups per XCD
    const int mt   = slot & 15;         // 16 mt-wgs per kz, dispatch-adjacent
    const int ss0 = (SS_TOTAL * kz) / KSPLIT;
    const int SSN = (SS_TOTAL * (kz + 1)) / KSPLIT - ss0;   // 36 or 37

    const int tid = threadIdx.x;
    const int wv  = tid >> 6;           // 0..7 = b-tile
    const int lane = tid & 63;
    const int r16 = lane & 15;
    const int kg  = lane >> 4;
    const int sw  = (r16 & 7) << 4;

    const __bf16* abase = Apk + ((size_t)ss0 * 8 + wv) * 2048 + lane * 8;

    f32x4 acc[3] = {};
    bf16x8 aA[4];

    // prologue: first tile in flight
    ISSUE_W(0, 0)

    int bcur = 0;
    for (int sl = 0; sl < SSN; ++sl) {
        wait_and_barrier();             // tile sl landed (all waves); buf
                                        // bcur^1's readers finished last iter
        if (sl + 1 < SSN) { ISSUE_W(sl + 1, bcur ^ 1) }
        LOAD_A(sl)
        COMPUTE(bcur)
        bcur ^= 1;
    }

    // D layout: col = lane&15 (m), row = (lane>>4)*4 + reg (b)   [m89/m91]
    float* pz = partial + (size_t)kz * (B_ * M_);
#pragma unroll
    for (int n = 0; n < 3; ++n) {
        const int m = mt * BN + n * 16 + r16;
#pragma unroll
        for (int r = 0; r < 4; ++r) {
            const int b = wv * 16 + kg * 4 + r;
            pz[(size_t)b * M_ + m] = acc[n][r];
        }
    }
}

// ---------------- post: reduce_k | mlp_gemm (block-partitioned) -------------
__global__ __launch_bounds__(256) void post(const float* __restrict__ pp,
                                            const float* __restrict__ EP,
                                            const float* __restrict__ Wm,
                                            float* __restrict__ out) {
    const int bid = blockIdx.x;
    if (bid < 1536) {
        int t = bid * 256 + threadIdx.x;
        int i = t % (B_ * M_);
        int zc = t / (B_ * M_);
        float s = 0.f;
#pragma unroll
        for (int z = zc * (KSPLIT / ZC); z < (zc + 1) * (KSPLIT / ZC); ++z)
            s += pp[(size_t)z * (B_ * M_) + i];
        atomicAdd(out + i, 0.1f * s);
    } else {
        const int wid   = ((bid - 1536) * 256 + threadIdx.x) >> 6;  // 0..383
        const int lane  = threadIdx.x & 63;
        const int bt    = wid & 7;
        const int mt    = wid >> 3;
        const int row16 = lane & 15;
        const int kgrp  = lane >> 4;
        const float* Arow = EP + (size_t)(bt*16 + row16) * (2*E_);
        const float* Brow = Wm + (size_t)(mt*16 + row16) * (2*E_);
        f32x4 acc = {};
        for (int k0 = 0; k0 < 2*E_; k0 += 32) {
            bf16x8 af = cvt8(Arow + k0 + kgrp*8);
            bf16x8 bv = cvt8(Brow + k0 + kgrp*8);
            acc = __builtin_amdgcn_mfma_f32_16x16x32_bf16(af, bv, acc, 0, 0, 0);
        }
        const int m = mt*16 + row16;
#pragma unroll
        for (int r = 0; r < 4; ++r) {
            const int b = bt*16 + kgrp*4 + r;
            atomicAdd(out + b * M_ + m, 0.9f * acc[r]);
        }
    }
}

extern "C" void kernel_launch(void* const* d_in, const int* in_sizes, int n_in,
                              void* d_out, int out_size, void* d_ws, size_t ws_size,
                              hipStream_t stream) {
    const float* se    = (const float*)d_in[0];
    const int*   be    = (const int*)  d_in[1];
    const float* mlp_w = (const float*)d_in[2];
    const float* mlp_b = (const float*)d_in[3];
    const float* fk_w  = (const float*)d_in[4];
    const float* fk_b  = (const float*)d_in[5];
    float* out = (float*)d_out;
    float* ep  = (float*)d_ws;                  // event_pair [128][1536] f32
    float* pp  = ep + (size_t)B_ * 2 * E_;      // partials [KSPLIT][128][768] f32
    __bf16* apk = (__bf16*)(pp + (size_t)KSPLIT * B_ * M_);  // packed A bf16

    const int be_stride = (in_sizes[1] == B_ * 4 * 2) ? 2 : 1;

    prep<<<3584, 256, 0, stream>>>(mlp_b, fk_b, se, be, be_stride, out, ep, apk);
    fk_gemm<<<MTN * KSPLIT, 512, 0, stream>>>(apk, fk_w, pp);
    post<<<1632, 256, 0, stream>>>(pp, ep, mlp_w, out);
}